// Round 4
// baseline (23065.814 us; speedup 1.0000x reference)
//
#include <hip/hip_runtime.h>
#include <hip/hip_bf16.h>

#define TSTEPS 4096
#define XD 256
#define HD 2048
#define YD 256
#define KD 2304   // XD + HD
#define NWG 256
#define NT 512

// ---- LDS layout (bytes) ----
#define WU_OFF 0
#define WR_OFF (8*KD*2)              // 36864
#define WC_OFF (16*KD*2)             // 73728
#define WY_OFF (24*KD*2)             // 110592
#define HBUF_OFF (WY_OFF + HD*4)     // 118784  h_{t-1} (2048 f, tag-perturbed)
#define ZBUF_OFF (HBUF_OFF + HD*4)   // 126976  z = r*h  (2048 f, tag-perturbed)
#define RED_OFF (ZBUF_OFF + HD*4)    // 135168  yp[8..15], bu[16..23], br[24..31], bc[32..39], by[40], hclean[56..63]
#define LDS_BYTES (RED_OFF + 256)    // 135424

// ---- workspace ----
// Hybrid relay: producers store TAGGED data (low 2 mantissa bits = epoch&3,
// fire-and-forget — no drain, no flags). WG0 is the ONLY reader during the
// produce window: it tag-polls the buffer, then broadcasts go. Consumers
// poll go (1 thread/WG), then load certified data once. Keeps R2's
// minimal-reader property (R1 lesson) while cutting ~2 serial LLC RTTs +
// the producer vmcnt stall per relay.
#define HGO_U32 0                    // 8 go lines (128B apart)
#define RGO_U32 256
#define WS_ZERO_BYTES 34816          // go lines + all buffers (tag 0; first epochs 1/2)
#define HB0_OFF 2048                 // h exchange buffers (8 KB each)
#define HB1_OFF 10240
#define RB0_OFF 18432                // z exchange buffers
#define RB1_OFF 26624

__device__ __forceinline__ float bflo(unsigned u){ return __uint_as_float(u << 16); }
__device__ __forceinline__ float bfhi(unsigned u){ return __uint_as_float(u & 0xffff0000u); }
__device__ __forceinline__ unsigned short f2bf(float f){
  unsigned b = __float_as_uint(f);
  b += 0x7fffu + ((b >> 16) & 1u);   // RTNE (inputs finite)
  return (unsigned short)(b >> 16);
}
__device__ __forceinline__ float sigmoidf_(float x){ return 1.0f / (1.0f + __expf(-x)); }

// Tagged publish: dword store is atomic (no tearing); low-2-bit epoch tag
// self-certifies visibility at LLC. <=3 ULP perturbation (R1: absmax unchanged).
__device__ __forceinline__ void storetag(float* p, float v, unsigned tag){
  unsigned b = (__float_as_uint(v) & ~3u) | tag;
  __hip_atomic_store((unsigned*)p, b, __ATOMIC_RELAXED, __HIP_MEMORY_SCOPE_AGENT);
}
__device__ __forceinline__ void flagst(unsigned* p, unsigned v){
  __hip_atomic_store(p, v, __ATOMIC_RELAXED, __HIP_MEMORY_SCOPE_AGENT);
}
// Proven serial go-poll (R2).
__device__ __forceinline__ void spinflag(const unsigned* p, unsigned epoch, long* budget){
  while (__hip_atomic_load(p, __ATOMIC_RELAXED, __HIP_MEMORY_SCOPE_AGENT) < epoch) {
    if (--(*budget) < 0) break;     // anti-hang: proceed rather than deadlock
    __builtin_amdgcn_s_sleep(1);
  }
}

// Hub tag-poll of one 16B chunk: certifies all 4 dwords carry the epoch tag;
// returns the certified chunk (WG0 then skips the data reload entirely).
// Single asm block per iteration (load + waitcnt) — R1-proven pattern.
__device__ __forceinline__ float4 pollchunk16(const float4* p, unsigned tag, long* budget){
  for (;;) {
    float4 r;
    asm volatile("global_load_dwordx4 %0, %1, off sc1\n\t"
                 "s_waitcnt vmcnt(0)"
                 : "=v"(r) : "v"(p) : "memory");
    unsigned m = (__float_as_uint(r.x)^tag) | (__float_as_uint(r.y)^tag)
               | (__float_as_uint(r.z)^tag) | (__float_as_uint(r.w)^tag);
    if ((m & 3u) == 0u) return r;
    if (--(*budget) < 0) return r;   // anti-hang
    __builtin_amdgcn_s_sleep(1);
  }
}

// Certified consumer load (post-go; sc1 = LLC-serviced).
__device__ __forceinline__ float4 cohload16(const float4* p){
  float4 r;
  asm volatile("global_load_dwordx4 %0, %1, off sc1\n\t"
               "s_waitcnt vmcnt(0)"
               : "=v"(r) : "v"(p) : "memory");
  return r;
}

// Unrolled K-chunk of a column dot.
template<int I0, int I1, int STRIDE>
__device__ __forceinline__ void dotacc(const float* v, const unsigned short* wcol,
                                       int lane, float4& acc){
  #pragma unroll
  for (int i = I0; i < I1; ++i) {
    int k = 4 * (lane + STRIDE * i);
    float4 vv = *(const float4*)(v + k);
    uint2  wq = *(const uint2*)(wcol + k);
    acc.x = fmaf(vv.x, bflo(wq.x), acc.x);
    acc.y = fmaf(vv.y, bfhi(wq.x), acc.y);
    acc.z = fmaf(vv.z, bflo(wq.y), acc.z);
    acc.w = fmaf(vv.w, bfhi(wq.y), acc.w);
  }
}
__device__ __forceinline__ void xpart(const float4 xq, const unsigned short* wcol,
                                      int l6, float4& acc){
  uint2 wq = *(const uint2*)(wcol + 4*l6);
  acc.x = fmaf(xq.x, bflo(wq.x), acc.x);
  acc.y = fmaf(xq.y, bfhi(wq.x), acc.y);
  acc.z = fmaf(xq.z, bflo(wq.y), acc.z);
  acc.w = fmaf(xq.w, bfhi(wq.y), acc.w);
}
__device__ __forceinline__ float redux64(float4 a){
  float s = (a.x + a.y) + (a.z + a.w);
  s += __shfl_xor(s, 32); s += __shfl_xor(s, 16); s += __shfl_xor(s, 8);
  s += __shfl_xor(s, 4);  s += __shfl_xor(s, 2);  s += __shfl_xor(s, 1);
  return s;
}

extern "C" __global__ void __launch_bounds__(NT)
gru_persistent(const float* __restrict__ x,  const float* __restrict__ h0,
               const float* __restrict__ Wc, const float* __restrict__ Wu,
               const float* __restrict__ Wr, const float* __restrict__ bc,
               const float* __restrict__ bu, const float* __restrict__ br,
               const float* __restrict__ Wy, const float* __restrict__ by,
               float* __restrict__ out, unsigned* wsu)
{
  extern __shared__ char smem[];
  unsigned short* wuS = (unsigned short*)(smem + WU_OFF);
  unsigned short* wrS = (unsigned short*)(smem + WR_OFF);
  unsigned short* wcS = (unsigned short*)(smem + WC_OFF);
  float* wyS   = (float*)(smem + WY_OFF);
  float* hbufS = (float*)(smem + HBUF_OFF);
  float* zbufS = (float*)(smem + ZBUF_OFF);
  float* red   = (float*)(smem + RED_OFF);

  unsigned* hgo = wsu + HGO_U32;
  unsigned* rgo = wsu + RGO_U32;
  float* hb[2] = { (float*)((char*)wsu + HB0_OFF), (float*)((char*)wsu + HB1_OFF) };
  float* rb[2] = { (float*)((char*)wsu + RB0_OFF), (float*)((char*)wsu + RB1_OFF) };

  const int wg = blockIdx.x, tid = threadIdx.x;
  const int col0 = 8 * wg;

  // ---- one-time weight staging: WG j owns gate cols [8j,8j+8), y col j ----
  for (int idx = tid; idx < 8*KD; idx += NT) {
    int c = idx & 7, k = idx >> 3;
    size_t g = (size_t)k * HD + col0 + c;   // W is [KD, 2048] row-major
    wuS[c*KD + k] = f2bf(Wu[g]);
    wrS[c*KD + k] = f2bf(Wr[g]);
    wcS[c*KD + k] = f2bf(Wc[g]);
  }
  for (int k = tid; k < HD; k += NT) wyS[k] = Wy[(size_t)k * YD + wg];
  if (tid < 8) {
    red[16+tid] = bu[col0+tid];
    red[24+tid] = br[col0+tid];
    red[32+tid] = bc[col0+tid];
    red[56+tid] = h0[col0+tid];     // clean fp32 carry of own h slice
  }
  if (tid == 0) red[40] = by[wg];
  __syncthreads();

  long budget = 20000000;

  const int w  = tid >> 6, l6 = tid & 63;          // wave / lane
  const unsigned short* ucol = wuS + w * KD;
  const unsigned short* rcol = wrS + w * KD;
  const unsigned short* ccol = wcS + w * KD;

  float4 xq = ((const float4*)x)[l6];              // per-thread x chunk
  float ureg = 0.f;

  // hidden-window work (off critical path): u gate, y[t-1] partials,
  // x_{t+1} prefetch. Runs under the z-relay latency.
  auto window = [&](int t){
    float4 au = make_float4(0.f, 0.f, 0.f, 0.f);
    xpart(xq, ucol, l6, au);
    dotacc<1, 9, 64>(hbufS - XD, ucol, l6, au);
    ureg = sigmoidf_(redux64(au) + red[16 + w]);
    int k = 256 * w + 4 * l6;
    float4 hv4 = *(const float4*)(hbufS + k);
    float4 wy4 = *(const float4*)(wyS + k);
    float ys = fmaf(hv4.x, wy4.x, fmaf(hv4.y, wy4.y, fmaf(hv4.z, wy4.z, hv4.w * wy4.w)));
    ys += __shfl_xor(ys, 32); ys += __shfl_xor(ys, 16); ys += __shfl_xor(ys, 8);
    ys += __shfl_xor(ys, 4);  ys += __shfl_xor(ys, 2);  ys += __shfl_xor(ys, 1);
    if (l6 == 0) red[8 + w] = ys;
    if (t + 1 < TSTEPS) xq = ((const float4*)(x + (size_t)(t+1) * XD))[l6];
  };

  for (int t = 0; t < TSTEPS; ++t) {
    // r x-part (registers) — ahead of the h relay
    float4 a1 = make_float4(0.f, 0.f, 0.f, 0.f);
    xpart(xq, rcol, l6, a1);

    // ---- h_{t-1} relay ----
    if (t == 0) {
      ((float4*)hbufS)[tid] = ((const float4*)h0)[tid];
    } else if (wg == 0) {
      // hub: certify tags, broadcast go, keep data (no reload)
      float4 hv = pollchunk16((const float4*)hb[(t+1)&1] + tid,
                              (unsigned)(t & 3), &budget);
      __syncthreads();
      if (tid < 8) flagst(hgo + tid*32, (unsigned)t);
      ((float4*)hbufS)[tid] = hv;
    } else {
      if (tid == 0) spinflag(hgo + (wg & 7)*32, (unsigned)t, &budget);
      __syncthreads();
      ((float4*)hbufS)[tid] = cohload16((const float4*)hb[(t+1)&1] + tid);
    }
    __syncthreads();                                 // S1: h visible in LDS

    // ---- critical r-dot: wave w -> col col0+w, h part ----
    dotacc<1, 9, 64>(hbufS - XD, rcol, l6, a1);
    {
      float s = redux64(a1);
      if (l6 == 0)
        storetag(rb[t&1] + col0 + w,
                 sigmoidf_(s + red[24 + w]) * red[56 + w],   // z = r*h (clean carry)
                 (unsigned)((t+1) & 3));                     // fire-and-forget
    }

    // c x-part with x_t BEFORE window's prefetch overwrites xq
    float4 a2 = make_float4(0.f, 0.f, 0.f, 0.f);
    xpart(xq, ccol, l6, a2);

    // ---- z relay ----
    if (wg == 0) {
      float4 zv = pollchunk16((const float4*)rb[t&1] + tid,
                              (unsigned)((t+1) & 3), &budget);
      __syncthreads();
      if (tid < 8) flagst(rgo + tid*32, (unsigned)(t+1));
      ((float4*)zbufS)[tid] = zv;
      window(t);                                     // hub does window after go
    } else {
      window(t);                                     // consumers: window first
      if (tid == 0) spinflag(rgo + (wg & 7)*32, (unsigned)(t+1), &budget);
      __syncthreads();
      ((float4*)zbufS)[tid] = cohload16((const float4*)rb[t&1] + tid);
    }
    __syncthreads();                                 // S2: z + y-partials visible

    // y[t-1] store: fire-and-forget, hidden under phase 2
    if (tid == 0 && t > 0) {
      float y = red[8]+red[9]+red[10]+red[11]+red[12]+red[13]+red[14]+red[15] + red[40];
      out[(size_t)(t-1) * YD + wg] = y;
    }

    // ---- phase 2: candidate (wave w -> col col0+w) ----
    dotacc<1, 9, 64>(zbufS - XD, ccol, l6, a2);
    {
      float s = redux64(a2);
      if (l6 == 0) {
        float cc = tanhf(s + red[32 + w]);
        float hp = red[56 + w];                      // clean fp32 carry
        float hn = cc * ureg + hp * (1.0f - ureg);
        red[56 + w] = hn;
        storetag(hb[t&1] + col0 + w, hn, (unsigned)((t+1) & 3));  // fire-and-forget
      }
    }
    // no trailing barrier: next h-relay's spin+sync guards LDS reuse
  }

  // ---- epilogue: y[T-1] and h_fin ----
  if (wg == 0) {
    float4 hv = pollchunk16((const float4*)hb[(TSTEPS-1)&1] + tid,
                            (unsigned)(TSTEPS & 3), &budget);
    __syncthreads();
    if (tid < 8) flagst(hgo + tid*32, (unsigned)TSTEPS);
    ((float4*)hbufS)[tid] = hv;
  } else {
    if (tid == 0) spinflag(hgo + (wg & 7)*32, (unsigned)TSTEPS, &budget);
    __syncthreads();
    ((float4*)hbufS)[tid] = cohload16((const float4*)hb[(TSTEPS-1)&1] + tid);
  }
  __syncthreads();
  {
    int k = 256 * w + 4 * l6;
    float4 hv4 = *(const float4*)(hbufS + k);
    float4 wy4 = *(const float4*)(wyS + k);
    float ys = fmaf(hv4.x, wy4.x, fmaf(hv4.y, wy4.y, fmaf(hv4.z, wy4.z, hv4.w * wy4.w)));
    ys += __shfl_xor(ys, 32); ys += __shfl_xor(ys, 16); ys += __shfl_xor(ys, 8);
    ys += __shfl_xor(ys, 4);  ys += __shfl_xor(ys, 2);  ys += __shfl_xor(ys, 1);
    if (l6 == 0) red[8 + w] = ys;
  }
  __syncthreads();
  if (tid == 0) {
    float y = red[8]+red[9]+red[10]+red[11]+red[12]+red[13]+red[14]+red[15] + red[40];
    out[(size_t)(TSTEPS-1) * YD + wg] = y;
  }
  if (tid < 8) out[(size_t)TSTEPS * YD + col0 + tid] = red[56 + tid];  // clean h_fin
}

extern "C" void kernel_launch(void* const* d_in, const int* in_sizes, int n_in,
                              void* d_out, int out_size, void* d_ws, size_t ws_size,
                              hipStream_t stream) {
  const float* x  = (const float*)d_in[0];
  const float* h0 = (const float*)d_in[1];
  const float* Wc = (const float*)d_in[2];
  const float* Wu = (const float*)d_in[3];
  const float* Wr = (const float*)d_in[4];
  const float* bc = (const float*)d_in[5];
  const float* bu = (const float*)d_in[6];
  const float* br = (const float*)d_in[7];
  const float* Wy = (const float*)d_in[8];
  const float* by = (const float*)d_in[9];
  float* out = (float*)d_out;
  unsigned* wsu = (unsigned*)d_ws;

  // >64 KB dynamic LDS on gfx950 (160 KB/CU). Idempotent; capture-safe.
  (void)hipFuncSetAttribute((const void*)gru_persistent,
                            hipFuncAttributeMaxDynamicSharedMemorySize, LDS_BYTES);
  (void)hipMemsetAsync(d_ws, 0, WS_ZERO_BYTES, stream);   // go + buffers (tag 0)
  gru_persistent<<<dim3(NWG), dim3(NT), LDS_BYTES, stream>>>(
      x, h0, Wc, Wu, Wr, bc, bu, br, Wy, by, out, wsu);
}